// Round 1
// baseline (188.427 us; speedup 1.0000x reference)
//
#include <hip/hip_runtime.h>
#include <math.h>
#include <float.h>

#define B_ 64
#define S_ 512
#define N_ 256
#define P_ 96
#define D_ 64
#define WIN_ 24
#define L_ 488   // S_ - WIN_
#define MID_ 7
#define PB_ (P_*B_)   // 6144

typedef unsigned short u16;
typedef __attribute__((ext_vector_type(4))) float floatx4;
typedef __attribute__((ext_vector_type(8))) short bf16x8;
#define MFMA16(a,b,c) __builtin_amdgcn_mfma_f32_16x16x32_bf16(a,b,c,0,0,0)

// workspace layout (BYTE offsets)
#define OFF_XST  ((size_t)0)                 // XsT bf16 [B][N][L]  15,990,784
#define OFF_TRT  ((size_t)15990784)          // trT bf16 [N][B][L]  15,990,784
#define OFF_WSE  ((size_t)31981568)          // season scores fp32 [B][P][L] 11,993,088
#define OFF_WSEB ((size_t)43974656)          // season weights bf16 [B][P][L] 5,996,544
#define OFF_WM   ((size_t)49971200)          // mid scores fp32 [B][MID][L] 874,496
#define OFF_WMB  ((size_t)50845696)          // mid weights bf16 437,248
#define OFF_PART ((size_t)51282944)          // trend partials bf16 [N][P][B] 3,145,728

__device__ inline u16 f2bf(float f) {
    union { float f; unsigned u; } v; v.f = f;
    unsigned r = v.u + 0x7FFFu + ((v.u >> 16) & 1u);
    return (u16)(r >> 16);
}
__device__ inline float bf2f(u16 u) {
    union { unsigned u; float f; } v; v.u = ((unsigned)u) << 16;
    return v.f;
}
__device__ inline bf16x8 cvt8(float4 a, float4 b) {
    bf16x8 r;
    r[0] = (short)f2bf(a.x); r[1] = (short)f2bf(a.y);
    r[2] = (short)f2bf(a.z); r[3] = (short)f2bf(a.w);
    r[4] = (short)f2bf(b.x); r[5] = (short)f2bf(b.y);
    r[6] = (short)f2bf(b.z); r[7] = (short)f2bf(b.w);
    return r;
}
// time2vec element d of embed at time t (d==0 linear, else sin)
__device__ inline float t2v(float t, int d, float w0v, float b0v,
                            const float* __restrict__ Wp,
                            const float* __restrict__ Bp) {
    return (d == 0) ? (t * w0v + b0v) : sinf(t * Wp[d - 1] + Bp[d - 1]);
}

// ---------------- Kernel 1: rolling-mean trend + season ----------------
__global__ __launch_bounds__(256) void k_trend(const float* __restrict__ X,
                                               u16* __restrict__ XST,
                                               u16* __restrict__ TRT) {
    int b = blockIdx.x, tile = blockIdx.y, n = threadIdx.x;
    __shared__ u16 tr_tile[256][34];
    __shared__ u16 xs_tile[256][34];
    const float* Xb = X + (size_t)b * S_ * N_ + n;
    int l0 = tile * 32;
    int cur = L_ - l0; if (cur > 32) cur = 32;    // 32 or 8 (tail)
    int s1 = WIN_ + l0;
    float wsum = 0.f;
    for (int s = s1 - WIN_; s < s1; ++s) wsum += Xb[(size_t)s * N_];
    for (int i = 0; i < cur; ++i) {
        int s = s1 + i;
        float xv = Xb[(size_t)s * N_];
        wsum += xv - Xb[(size_t)(s - WIN_) * N_];
        float tr = wsum * (1.f / WIN_);
        tr_tile[n][i] = f2bf(tr);
        xs_tile[n][i] = f2bf(xv - tr);
    }
    __syncthreads();
    int wv = threadIdx.x >> 6, lane = threadIdx.x & 63;
    int half = lane >> 5, c = lane & 31;          // 2 rows per instruction
    if (c < cur) {
        for (int it = 0; it < 32; ++it) {
            int r = it * 8 + wv * 2 + half;
            TRT[(size_t)r * (B_ * L_) + (size_t)b * L_ + l0 + c] = tr_tile[r][c];
            XST[((size_t)b * N_ + r) * L_ + l0 + c] = xs_tile[r][c];
        }
    }
}

// ------- Kernel 2 (MERGED dispatch): trend GEMM  |  scores ----------------
// bid < 256: trend GEMM, DIRECT global->register MFMA (no LDS, no barriers,
//            register double-buffered depth-1 prefetch).
// bid >= 256: season+mid raw scores (unchanged body).
__global__ __launch_bounds__(256) void k_gemm_scores(const float* __restrict__ Wt_g,
                                                     const float* __restrict__ bt,
                                                     const u16* __restrict__ TRT,
                                                     u16* __restrict__ part,
                                                     const float* __restrict__ T,
                                                     const float* __restrict__ w0,
                                                     const float* __restrict__ b0,
                                                     const float* __restrict__ Wp,
                                                     const float* __restrict__ Bp,
                                                     float* __restrict__ WSE,
                                                     float* __restrict__ WM_g) {
    __shared__ __align__(16) char smem_raw[45424];   // used by scores branch only
    int bid = blockIdx.x, tid = threadIdx.x;
    if (bid < 256) {
        // ============ trend GEMM: one block per n, 96x64, K=488 ===========
        // wave grid 2x2: wr = row half (48 rows = 3 frags), wc = col half
        // (32 cols = 2 frags). Fragment loads go straight from global:
        // lane(fr,quad) reads row fr, k-bytes [k0+quad*8 .. +8) — a wave
        // covers 16 rows x 128B contiguous per load instruction.
        int n = bid;
        int lane = tid & 63, wv = tid >> 6;
        int wr = wv >> 1, wc = wv & 1;
        int fr = lane & 15, quad = lane >> 4;
        int qoff = quad * 8;
        const float* Wn = Wt_g + (size_t)n * P_ * L_;
        const u16*  Tn = TRT + (size_t)n * (B_ * L_);
        const float* ap0 = Wn + (size_t)(wr * 48 +  0 + fr) * L_;
        const float* ap1 = Wn + (size_t)(wr * 48 + 16 + fr) * L_;
        const float* ap2 = Wn + (size_t)(wr * 48 + 32 + fr) * L_;
        const u16*  bp0 = Tn + (size_t)(wc * 32 +  0 + fr) * L_;
        const u16*  bp1 = Tn + (size_t)(wc * 32 + 16 + fr) * L_;
        floatx4 acc[3][2];
#pragma unroll
        for (int j = 0; j < 3; ++j)
#pragma unroll
            for (int i = 0; i < 2; ++i) acc[j][i] = (floatx4){0.f, 0.f, 0.f, 0.f};

        float4 fa[2][3][2];   // [buf][frag][half] raw fp32 W
        uint4  fb[2][2];      // [buf][frag] bf16 trT

        auto FETCHF = [&](int c, int s) {   // full 32-wide K-step
            int kq = c * 32 + qoff;
            fa[s][0][0] = *(const float4*)(ap0 + kq);
            fa[s][0][1] = *(const float4*)(ap0 + kq + 4);
            fa[s][1][0] = *(const float4*)(ap1 + kq);
            fa[s][1][1] = *(const float4*)(ap1 + kq + 4);
            fa[s][2][0] = *(const float4*)(ap2 + kq);
            fa[s][2][1] = *(const float4*)(ap2 + kq + 4);
            fb[s][0] = *(const uint4*)(bp0 + kq);
            fb[s][1] = *(const uint4*)(bp1 + kq);
        };
        auto FETCHT = [&](int s) {          // tail: k = 480..487, quad 0 only
            int kq = 480 + qoff;
            bool ok = (quad == 0);
            float4 z4 = make_float4(0.f, 0.f, 0.f, 0.f);
            uint4  zu = make_uint4(0u, 0u, 0u, 0u);
            fa[s][0][0] = ok ? *(const float4*)(ap0 + kq) : z4;
            fa[s][0][1] = ok ? *(const float4*)(ap0 + kq + 4) : z4;
            fa[s][1][0] = ok ? *(const float4*)(ap1 + kq) : z4;
            fa[s][1][1] = ok ? *(const float4*)(ap1 + kq + 4) : z4;
            fa[s][2][0] = ok ? *(const float4*)(ap2 + kq) : z4;
            fa[s][2][1] = ok ? *(const float4*)(ap2 + kq + 4) : z4;
            fb[s][0] = ok ? *(const uint4*)(bp0 + kq) : zu;
            fb[s][1] = ok ? *(const uint4*)(bp1 + kq) : zu;
        };
        auto STEP = [&](int s) {
            bf16x8 b0f = __builtin_bit_cast(bf16x8, fb[s][0]);
            bf16x8 b1f = __builtin_bit_cast(bf16x8, fb[s][1]);
            bf16x8 a0f = cvt8(fa[s][0][0], fa[s][0][1]);
            bf16x8 a1f = cvt8(fa[s][1][0], fa[s][1][1]);
            bf16x8 a2f = cvt8(fa[s][2][0], fa[s][2][1]);
            acc[0][0] = MFMA16(a0f, b0f, acc[0][0]);
            acc[0][1] = MFMA16(a0f, b1f, acc[0][1]);
            acc[1][0] = MFMA16(a1f, b0f, acc[1][0]);
            acc[1][1] = MFMA16(a1f, b1f, acc[1][1]);
            acc[2][0] = MFMA16(a2f, b0f, acc[2][0]);
            acc[2][1] = MFMA16(a2f, b1f, acc[2][1]);
        };

        FETCHF(0, 0);
#pragma unroll
        for (int c = 1; c < 15; ++c) { FETCHF(c, c & 1); STEP((c & 1) ^ 1); }
        FETCHT(1);
        STEP(0);
        STEP(1);

        // epilogue: bias + direct bf16 stores to PART [n][p][b]
#pragma unroll
        for (int j = 0; j < 3; ++j) {
            int p0 = wr * 48 + j * 16 + quad * 4;
#pragma unroll
            for (int i = 0; i < 2; ++i) {
                int bc = wc * 32 + i * 16 + fr;
                u16* dst = part + (size_t)n * PB_ + (size_t)p0 * B_ + bc;
#pragma unroll
                for (int r = 0; r < 4; ++r)
                    dst[(size_t)r * B_] =
                        f2bf(acc[j][i][r] + bt[(size_t)(p0 + r) * N_ + n]);
            }
        }
    } else {
        // ============ merged season + mid raw scores (unchanged) ==========
        int r = bid - 256;
        int b = r >> 3, kt = r & 7;
        float* W = WSE + (size_t)b * P_ * L_;
        float* WM = WM_g + (size_t)b * MID_ * L_;
        float* Al = (float*)smem_raw;            // [96][68]
        float* qv = Al + 96 * 68;                // [7][68]
        float* Bl = qv + 7 * 68;                 // [64][68]
        float w0v = w0[0], b0v = b0[0];
        float Tlast = T[(size_t)b * S_ + (S_ - 1)];
        for (int idx = tid; idx < 96 * 64; idx += 256) {
            int q = idx >> 6, d = idx & 63;
            Al[q * 68 + d] = t2v(Tlast + (float)(q + 1), d, w0v, b0v, Wp, Bp);
        }
        for (int idx = tid; idx < 7 * 64; idx += 256) {
            int q = idx >> 6, d = idx & 63;
            float t = T[(size_t)b * S_ + WIN_ + (L_ - MID_ + q)];
            qv[q * 68 + d] = t2v(t, d, w0v, b0v, Wp, Bp);
        }
        int k0 = kt * 64;
        for (int idx = tid; idx < 64 * 64; idx += 256) {
            int kk = idx >> 6, d = idx & 63;
            int k = k0 + kk;
            float v = 0.f;
            if (k < L_) v = t2v(T[(size_t)b * S_ + WIN_ + k], d, w0v, b0v, Wp, Bp);
            Bl[kk * 68 + d] = v;
        }
        __syncthreads();
        {   // season scores: C[96 q][64 k], 6x4 register tile
            int qt = tid >> 4, ktl = tid & 15;
            float acc[6][4] = {};
            for (int d = 0; d < 64; d += 4) {
                float4 av[6], bv[4];
#pragma unroll
                for (int j = 0; j < 6; ++j) av[j] = *(const float4*)&Al[(qt + 16 * j) * 68 + d];
#pragma unroll
                for (int i = 0; i < 4; ++i) bv[i] = *(const float4*)&Bl[(ktl + 16 * i) * 68 + d];
#pragma unroll
                for (int j = 0; j < 6; ++j)
#pragma unroll
                    for (int i = 0; i < 4; ++i)
                        acc[j][i] += av[j].x * bv[i].x + av[j].y * bv[i].y +
                                     av[j].z * bv[i].z + av[j].w * bv[i].w;
            }
#pragma unroll
            for (int j = 0; j < 6; ++j) {
                int q = qt + 16 * j;
#pragma unroll
                for (int i = 0; i < 4; ++i) {
                    int k = k0 + ktl + 16 * i;
                    if (k < L_) W[(size_t)q * L_ + k] = acc[j][i] * 0.125f;
                }
            }
        }
        {   // mid masked scores over the same ET tile
            int klane = tid & 63, qs = tid >> 6;
            int q0 = qs, q1 = qs + 4;
            float a0 = 0.f, a1 = 0.f;
            for (int d = 0; d < 64; ++d) {
                float e = Bl[klane * 68 + d];
                a0 += e * qv[q0 * 68 + d];
                if (q1 < 7) a1 += e * qv[q1 * 68 + d];
            }
            int k = k0 + klane;
            if (k < L_) {
                WM[(size_t)q0 * L_ + k] = (k < L_ - MID_ + q0) ? a0 * 0.125f : -FLT_MAX;
                if (q1 < 7)
                    WM[(size_t)q1 * L_ + k] = (k < L_ - MID_ + q1) ? a1 * 0.125f : -FLT_MAX;
            }
        }
    }
}

// ------- Kernel 3 (MERGED dispatch): reduce_trend | softmax se+mid --------
__global__ __launch_bounds__(256) void k_reduce_softmax(const u16* __restrict__ part,
                                                        float* __restrict__ out0,
                                                        const float* __restrict__ WSE,
                                                        u16* __restrict__ WSEB,
                                                        const float* __restrict__ WM_g,
                                                        u16* __restrict__ WMB) {
    __shared__ __align__(16) char smem_raw[8320];
    int bid = blockIdx.x, tid = threadIdx.x;
    if (bid < 768) {
        // transpose bf16 partial[n][p][b] -> fp32 out0 [b][p][n]
        int nt = bid & 7, p = bid >> 3;
        float* t = (float*)smem_raw;             // [32][65]
        int n0 = nt * 32;
        for (int idx = tid; idx < 512; idx += 256) {
            int i = idx >> 4, j4 = (idx & 15) * 4;
            ushort4 v = *(const ushort4*)&part[(size_t)(n0 + i) * PB_ + p * 64 + j4];
            t[i * 65 + j4 + 0] = bf2f(v.x); t[i * 65 + j4 + 1] = bf2f(v.y);
            t[i * 65 + j4 + 2] = bf2f(v.z); t[i * 65 + j4 + 3] = bf2f(v.w);
        }
        __syncthreads();
        for (int idx = tid; idx < 2048; idx += 256) {
            int bb = idx >> 5, nl = idx & 31;
            out0[((size_t)bb * P_ + p) * N_ + n0 + nl] = t[nl * 65 + bb];
        }
    } else {
        int row = (bid - 768) * 4 + (tid >> 6);  // 6592 rows total
        int lane = tid & 63;
        const float* base;
        u16* out;
        if (row < 6144) {
            base = WSE + (size_t)row * L_;
            out = WSEB + (size_t)row * L_;
        } else {
            base = WM_g + (size_t)(row - 6144) * L_;
            out = WMB + (size_t)(row - 6144) * L_;
        }
        float v[8], m = -FLT_MAX;
#pragma unroll
        for (int i = 0; i < 8; ++i) {
            int idx = i * 64 + lane;
            v[i] = (idx < L_) ? base[idx] : -FLT_MAX;
            m = fmaxf(m, v[i]);
        }
        for (int off = 32; off; off >>= 1) m = fmaxf(m, __shfl_xor(m, off));
        float s = 0.f;
#pragma unroll
        for (int i = 0; i < 8; ++i) { float e = expf(v[i] - m); v[i] = e; s += e; }
        for (int off = 32; off; off >>= 1) s += __shfl_xor(s, off);
        float inv = 1.f / s;
#pragma unroll
        for (int i = 0; i < 8; ++i) {
            int idx = i * 64 + lane;
            if (idx < L_) out[idx] = f2bf(v[i] * inv);
        }
    }
}

// ------- Kernel 4 (MERGED dispatch): season PV | mid PV -------------------
// grid (B, 12): y<4 -> season PV (nt=y), direct global->register MFMA,
// no LDS/barriers; y>=4 -> mid PV (nt=y-4), unchanged.
__global__ __launch_bounds__(256) void k_pv(const u16* __restrict__ WSEB,
                                            const u16* __restrict__ XST,
                                            float* __restrict__ out0,
                                            const u16* __restrict__ WMB,
                                            float* __restrict__ out1) {
    __shared__ __align__(16) char smem_raw[21056];   // mid branch only
    int b = blockIdx.x, y = blockIdx.y, tid = threadIdx.x;
    if (y < 4) {
        // ===== season PV: 96(p) x 64(n) per block, K=488, all-bf16 ========
        int nt = y;
        int lane = tid & 63, wv = tid >> 6;
        int wr = wv >> 1, wc = wv & 1;
        int fr = lane & 15, quad = lane >> 4;
        int qoff = quad * 8;
        const u16* Wa = WSEB + (size_t)b * P_ * L_;
        const u16* Xb = XST + ((size_t)b * N_ + nt * 64) * L_;
        const u16* ap0 = Wa + (size_t)(wr * 48 +  0 + fr) * L_;
        const u16* ap1 = Wa + (size_t)(wr * 48 + 16 + fr) * L_;
        const u16* ap2 = Wa + (size_t)(wr * 48 + 32 + fr) * L_;
        const u16* bp0 = Xb + (size_t)(wc * 32 +  0 + fr) * L_;
        const u16* bp1 = Xb + (size_t)(wc * 32 + 16 + fr) * L_;
        floatx4 acc[3][2];
#pragma unroll
        for (int j = 0; j < 3; ++j)
#pragma unroll
            for (int i = 0; i < 2; ++i) acc[j][i] = (floatx4){0.f, 0.f, 0.f, 0.f};

        uint4 fa[2][3], fb[2][2];

        auto FETCHF = [&](int c, int s) {
            int kq = c * 32 + qoff;
            fa[s][0] = *(const uint4*)(ap0 + kq);
            fa[s][1] = *(const uint4*)(ap1 + kq);
            fa[s][2] = *(const uint4*)(ap2 + kq);
            fb[s][0] = *(const uint4*)(bp0 + kq);
            fb[s][1] = *(const uint4*)(bp1 + kq);
        };
        auto FETCHT = [&](int s) {
            int kq = 480 + qoff;
            bool ok = (quad == 0);
            uint4 zu = make_uint4(0u, 0u, 0u, 0u);
            fa[s][0] = ok ? *(const uint4*)(ap0 + kq) : zu;
            fa[s][1] = ok ? *(const uint4*)(ap1 + kq) : zu;
            fa[s][2] = ok ? *(const uint4*)(ap2 + kq) : zu;
            fb[s][0] = ok ? *(const uint4*)(bp0 + kq) : zu;
            fb[s][1] = ok ? *(const uint4*)(bp1 + kq) : zu;
        };
        auto STEP = [&](int s) {
            bf16x8 a0f = __builtin_bit_cast(bf16x8, fa[s][0]);
            bf16x8 a1f = __builtin_bit_cast(bf16x8, fa[s][1]);
            bf16x8 a2f = __builtin_bit_cast(bf16x8, fa[s][2]);
            bf16x8 b0f = __builtin_bit_cast(bf16x8, fb[s][0]);
            bf16x8 b1f = __builtin_bit_cast(bf16x8, fb[s][1]);
            acc[0][0] = MFMA16(a0f, b0f, acc[0][0]);
            acc[0][1] = MFMA16(a0f, b1f, acc[0][1]);
            acc[1][0] = MFMA16(a1f, b0f, acc[1][0]);
            acc[1][1] = MFMA16(a1f, b1f, acc[1][1]);
            acc[2][0] = MFMA16(a2f, b0f, acc[2][0]);
            acc[2][1] = MFMA16(a2f, b1f, acc[2][1]);
        };

        FETCHF(0, 0);
#pragma unroll
        for (int c = 1; c < 15; ++c) { FETCHF(c, c & 1); STEP((c & 1) ^ 1); }
        FETCHT(1);
        STEP(0);
        STEP(1);

        // epilogue: direct fp32 read-modify-write into out0 (+= pred_trend)
        float* o = out0 + (size_t)b * P_ * N_ + nt * 64;
#pragma unroll
        for (int j = 0; j < 3; ++j) {
            int p0 = wr * 48 + j * 16 + quad * 4;
#pragma unroll
            for (int i = 0; i < 2; ++i) {
                int c = wc * 32 + i * 16 + fr;
#pragma unroll
                for (int r = 0; r < 4; ++r) {
                    float* dp = &o[(size_t)(p0 + r) * N_ + c];
                    *dp += acc[j][i][r];
                }
            }
        }
    } else {
        // ================ mid PV from XsT + bf16 weights ==================
        int nt = y - 4;
        int nl = tid & 31, ks = tid >> 5;        // 8 k-slices of 61
        float* wl = (float*)smem_raw;            // [7*L_] = 13,664 B
        float* partl = (float*)(smem_raw + 13664); // [8][7][33] = 7,392 B
        const u16* WMb = WMB + (size_t)b * MID_ * L_;
        for (int idx = tid; idx < 7 * L_; idx += 256) wl[idx] = bf2f(WMb[idx]);
        __syncthreads();
        const u16* xrow = XST + ((size_t)b * N_ + nt * 32 + nl) * L_;
        float acc[7] = {};
        int kbeg = ks * 61, kend = kbeg + 61;
        for (int k = kbeg; k < kend; ++k) {
            float xv = bf2f(xrow[k]);
#pragma unroll
            for (int q = 0; q < 7; ++q) acc[q] += wl[q * L_ + k] * xv;
        }
#pragma unroll
        for (int q = 0; q < 7; ++q) partl[(ks * 7 + q) * 33 + nl] = acc[q];
        __syncthreads();
        if (ks == 0) {
#pragma unroll
            for (int q = 0; q < 7; ++q) {
                float v = 0.f;
#pragma unroll
                for (int s = 0; s < 8; ++s) v += partl[(s * 7 + q) * 33 + nl];
                out1[((size_t)b * MID_ + q) * N_ + nt * 32 + nl] = v;
            }
        }
    }
}

extern "C" void kernel_launch(void* const* d_in, const int* in_sizes, int n_in,
                              void* d_out, int out_size, void* d_ws, size_t ws_size,
                              hipStream_t stream) {
    (void)in_sizes; (void)n_in; (void)out_size; (void)ws_size;
    const float* X  = (const float*)d_in[0];
    const float* T  = (const float*)d_in[1];
    const float* Wt = (const float*)d_in[2];
    const float* bt = (const float*)d_in[3];
    const float* w0 = (const float*)d_in[4];
    const float* b0 = (const float*)d_in[5];
    const float* Wp = (const float*)d_in[6];
    const float* Bp = (const float*)d_in[7];
    float* out = (float*)d_out;
    char* w8 = (char*)d_ws;
    float* out1 = out + (size_t)B_ * P_ * N_;

    u16*   XST  = (u16*)(w8 + OFF_XST);
    u16*   TRT  = (u16*)(w8 + OFF_TRT);
    float* WSE  = (float*)(w8 + OFF_WSE);
    u16*   WSEB = (u16*)(w8 + OFF_WSEB);
    float* WM   = (float*)(w8 + OFF_WM);
    u16*   WMB  = (u16*)(w8 + OFF_WMB);
    u16*   PART = (u16*)(w8 + OFF_PART);

    hipLaunchKernelGGL(k_trend, dim3(B_, 16), dim3(256), 0, stream, X, XST, TRT);
    hipLaunchKernelGGL(k_gemm_scores, dim3(768), dim3(256), 0, stream,
                       Wt, bt, TRT, PART, T, w0, b0, Wp, Bp, WSE, WM);
    hipLaunchKernelGGL(k_reduce_softmax, dim3(768 + 1648), dim3(256), 0, stream,
                       PART, out, WSE, WSEB, WM, WMB);
    hipLaunchKernelGGL(k_pv, dim3(B_, 12), dim3(256), 0, stream,
                       WSEB, XST, out, WMB, out1);
}